// Round 1
// baseline (449.045 us; speedup 1.0000x reference)
//
#include <hip/hip_runtime.h>
#include <stdint.h>

// ---------------- problem constants ----------------
#define GN   33
#define GG   1089      // 33*33
#define GGG  35937     // 33^3
#define BATCH 4
#define KK   8
#define RR   8
#define HLR  256
#define WLR  256
#define HFULL 1080
#define WFULL 1920
#define NPIX (HFULL*WFULL)          // 2,073,600 per channel
#define NPIX4 (NPIX/4)              // 518,400 float4 per channel

// d_out layout (floats): out | alpha | delta | L | delta_norm
#define OUT_ALPHA 24883200
#define OUT_DELTA 24883232
#define OUT_L     25314476
#define OUT_DNORM 25745720

// workspace layout (float offsets). Total ~10.3 MiB.
#define WS_H1WP   0          // 4*16*128*128
#define WS_H1RP   1048576
#define WS_STATS  2097152    // meanwp(128) meanrp(128) dnorm(1) -> memset region
#define WS_MEANWP 2097152
#define WS_MEANRP 2097280
#define WS_DNORM  2097408
#define WS_ALPHA  2097412    // 32
#define WS_U      2097444    // 4*264
#define WS_V      2098500
#define WS_W      2099556
#define WS_C      2100612    // 4*24
#define WS_LPAD   2100712    // byte offset 8402848, 16B aligned; 4*35937*8 ushorts

__device__ __forceinline__ unsigned short f2bf(float f) {
    unsigned u = __float_as_uint(f);
    unsigned r = (u + 0x7fffu + ((u >> 16) & 1u)) >> 16;
    return (unsigned short)r;
}
__device__ __forceinline__ float bflo(unsigned u) { return __uint_as_float(u << 16); }
__device__ __forceinline__ float bfhi(unsigned u) { return __uint_as_float(u & 0xffff0000u); }

// ---------------- conv1: 3->16 ch, 3x3 s2 p1, relu ----------------
__global__ __launch_bounds__(256) void conv1_kernel(
    const float* __restrict__ img,
    const float* __restrict__ w_wp, const float* __restrict__ b_wp,
    const float* __restrict__ w_rp, const float* __restrict__ b_rp,
    float* __restrict__ ws)
{
    const int enc = blockIdx.z;
    const float* w  = enc ? w_rp : w_wp;
    const float* bb = enc ? b_rp : b_wp;
    float* out = ws + (enc ? WS_H1RP : WS_H1WP);
    const int plane = blockIdx.y;            // b*16 + o
    const int b = plane >> 4, o = plane & 15;
    const int p = blockIdx.x * 256 + threadIdx.x;   // 0..16383
    const int i = p >> 7, j = p & 127;
    const float* wo  = w + o * 27;
    const float* imb = img + (size_t)b * 3 * HLR * WLR;
    float acc = bb[o];
    #pragma unroll
    for (int c = 0; c < 3; ++c) {
        #pragma unroll
        for (int ky = 0; ky < 3; ++ky) {
            const int iy = 2*i - 1 + ky;
            if ((unsigned)iy < (unsigned)HLR) {
                #pragma unroll
                for (int kx = 0; kx < 3; ++kx) {
                    const int ix = 2*j - 1 + kx;
                    if ((unsigned)ix < (unsigned)WLR)
                        acc += wo[c*9 + ky*3 + kx] * imb[(c*HLR + iy)*WLR + ix];
                }
            }
        }
    }
    out[(plane << 14) + p] = fmaxf(acc, 0.f);
}

// ---------------- conv2: 16->32 ch, 3x3 s2 p1, relu, + spatial-mean accumulate ----------------
__global__ __launch_bounds__(256) void conv2_kernel(
    const float* __restrict__ w_wp, const float* __restrict__ b_wp,
    const float* __restrict__ w_rp, const float* __restrict__ b_rp,
    float* __restrict__ ws)
{
    const int enc = blockIdx.z;
    const float* w  = enc ? w_rp : w_wp;
    const float* bb = enc ? b_rp : b_wp;
    const float* h1 = ws + (enc ? WS_H1RP : WS_H1WP);
    float* mean = ws + (enc ? WS_MEANRP : WS_MEANWP);
    const int plane = blockIdx.y;            // b*32 + o
    const int b = plane >> 5, o = plane & 31;
    const int p = blockIdx.x * 256 + threadIdx.x;   // 0..4095
    const int i = p >> 6, j = p & 63;
    const float* wo = w + o * 144;
    const float* hb = h1 + (size_t)b * 16 * 128 * 128;
    float acc = bb[o];
    for (int c = 0; c < 16; ++c) {
        #pragma unroll
        for (int ky = 0; ky < 3; ++ky) {
            const int iy = 2*i - 1 + ky;
            if ((unsigned)iy < 128u) {
                #pragma unroll
                for (int kx = 0; kx < 3; ++kx) {
                    const int ix = 2*j - 1 + kx;
                    if ((unsigned)ix < 128u)
                        acc += wo[c*9 + ky*3 + kx] * hb[(c*128 + iy)*128 + ix];
                }
            }
        }
    }
    float v = fmaxf(acc, 0.f);
    #pragma unroll
    for (int off = 32; off; off >>= 1) v += __shfl_down(v, off);
    __shared__ float s[4];
    const int lane = threadIdx.x & 63, wid = threadIdx.x >> 6;
    if (!lane) s[wid] = v;
    __syncthreads();
    if (!threadIdx.x) atomicAdd(&mean[plane], s[0] + s[1] + s[2] + s[3]);
}

// ---------------- heads: alpha, u, v, w, c ----------------
__global__ __launch_bounds__(256) void head_kernel(
    const float* __restrict__ wp_fc_w, const float* __restrict__ wp_fc_b,
    const float* __restrict__ fcu_w, const float* __restrict__ fcu_b,
    const float* __restrict__ fcv_w, const float* __restrict__ fcv_b,
    const float* __restrict__ fcw_w, const float* __restrict__ fcw_b,
    const float* __restrict__ fcc_w, const float* __restrict__ fcc_b,
    float* __restrict__ ws, float* __restrict__ dout)
{
    const int it = blockIdx.x * 256 + threadIdx.x;
    if (it >= BATCH * 824) return;
    const int b = it / 824, j = it - b * 824;
    const float msc = 1.0f / 4096.0f;
    const float* mw = ws + WS_MEANWP + b * 32;
    const float* mr = ws + WS_MEANRP + b * 32;
    if (j < 8) {
        const float* row = wp_fc_w + j * 32;
        float acc = wp_fc_b[j];
        #pragma unroll 8
        for (int q = 0; q < 32; ++q) acc += row[q] * (mw[q] * msc);
        ws[WS_ALPHA + b*8 + j] = acc;
        dout[OUT_ALPHA + b*8 + j] = acc;
    } else if (j < 272) {
        const int jj = j - 8;
        const float* row = fcu_w + jj * 32;
        float acc = fcu_b[jj];
        #pragma unroll 8
        for (int q = 0; q < 32; ++q) acc += row[q] * (mr[q] * msc);
        ws[WS_U + b*264 + jj] = acc;
    } else if (j < 536) {
        const int jj = j - 272;
        const float* row = fcv_w + jj * 32;
        float acc = fcv_b[jj];
        #pragma unroll 8
        for (int q = 0; q < 32; ++q) acc += row[q] * (mr[q] * msc);
        ws[WS_V + b*264 + jj] = acc;
    } else if (j < 800) {
        const int jj = j - 536;
        const float* row = fcw_w + jj * 32;
        float acc = fcw_b[jj];
        #pragma unroll 8
        for (int q = 0; q < 32; ++q) acc += row[q] * (mr[q] * msc);
        ws[WS_W + b*264 + jj] = acc;
    } else {
        const int jj = j - 800;
        const float* row = fcc_w + jj * 32;
        float acc = fcc_b[jj];
        #pragma unroll 8
        for (int q = 0; q < 32; ++q) acc += row[q] * (mr[q] * msc);
        ws[WS_C + b*24 + jj] = acc;
    }
}

// ---------------- LUT build: delta, L, bf16 z-pair LUT, |delta| sum ----------------
__global__ __launch_bounds__(256) void lut_build_kernel(
    const float* __restrict__ bases,
    float* __restrict__ ws, float* __restrict__ dout)
{
    const int tid = blockIdx.x * 256 + threadIdx.x;
    float sum3 = 0.f;
    if (tid < BATCH * GGG) {
        const int b = tid / GGG, s = tid - b * GGG;
        const int x = s / GG;
        const int rem = s - x * GG;
        const int y = rem / GN, z = rem - y * GN;
        const float* U = ws + WS_U + b * 264;
        const float* V = ws + WS_V + b * 264;
        const float* W = ws + WS_W + b * 264;
        const float* C = ws + WS_C + b * 24;
        const float* A = ws + WS_ALPHA + b * 8;
        float d0 = 0.f, d1 = 0.f, d2 = 0.f;
        #pragma unroll
        for (int r = 0; r < RR; ++r) {
            const float t = U[r*GN + x] * V[r*GN + y] * W[r*GN + z];
            d0 += t * C[r*3 + 0];
            d1 += t * C[r*3 + 1];
            d2 += t * C[r*3 + 2];
        }
        float l0 = d0, l1 = d1, l2 = d2;
        #pragma unroll
        for (int k = 0; k < KK; ++k) {
            const float a = A[k];
            const float* bp = bases + ((size_t)k * GGG + s) * 3;
            l0 += a * bp[0];
            l1 += a * bp[1];
            l2 += a * bp[2];
        }
        const size_t o3 = (size_t)tid * 3;
        dout[OUT_DELTA + o3 + 0] = d0;
        dout[OUT_DELTA + o3 + 1] = d1;
        dout[OUT_DELTA + o3 + 2] = d2;
        dout[OUT_L + o3 + 0] = l0;
        dout[OUT_L + o3 + 1] = l1;
        dout[OUT_L + o3 + 2] = l2;
        unsigned short* lp = (unsigned short*)(ws + WS_LPAD);
        const size_t e = (size_t)tid * 8;
        lp[e + 0] = f2bf(l0); lp[e + 1] = f2bf(l1); lp[e + 2] = f2bf(l2);
        if (z > 0) {  // this site is the z+1 corner of entry (x, y, z-1)
            lp[e - 8 + 4] = f2bf(l0); lp[e - 8 + 5] = f2bf(l1); lp[e - 8 + 6] = f2bf(l2);
        }
        sum3 = fabsf(d0) + fabsf(d1) + fabsf(d2);
    }
    #pragma unroll
    for (int off = 32; off; off >>= 1) sum3 += __shfl_down(sum3, off);
    __shared__ float s4[4];
    const int lane = threadIdx.x & 63, wid = threadIdx.x >> 6;
    if (!lane) s4[wid] = sum3;
    __syncthreads();
    if (!threadIdx.x) atomicAdd(ws + WS_DNORM, s4[0] + s4[1] + s4[2] + s4[3]);
}

__global__ void dnorm_kernel(const float* __restrict__ ws, float* __restrict__ dout)
{
    dout[OUT_DNORM] = ws[WS_DNORM] * (1.0f / (float)(BATCH * GGG * 3));
}

// ---------------- trilinear apply ----------------
__global__ __launch_bounds__(256) void apply_kernel(
    const float* __restrict__ img,
    const float* __restrict__ ws, float* __restrict__ dout)
{
    const int tid = blockIdx.x * 256 + threadIdx.x;     // 0..BATCH*NPIX4-1
    const int b = tid / NPIX4;
    const int q = tid - b * NPIX4;
    const float4* base = (const float4*)(img + (size_t)b * 3 * NPIX);
    const float4 rv = base[q];
    const float4 gv = base[NPIX4 + q];
    const float4 bv = base[2 * NPIX4 + q];
    const uint4* lut = (const uint4*)((const unsigned short*)(ws + WS_LPAD) + (size_t)b * GGG * 8);

    float rr[4] = {rv.x, rv.y, rv.z, rv.w};
    float gg[4] = {gv.x, gv.y, gv.z, gv.w};
    float bb[4] = {bv.x, bv.y, bv.z, bv.w};
    float o0[4], o1[4], o2[4];

    #pragma unroll
    for (int t = 0; t < 4; ++t) {
        const float xf = fminf(fmaxf(rr[t] * 32.f, 0.f), 31.999998f);
        const float yf = fminf(fmaxf(gg[t] * 32.f, 0.f), 31.999998f);
        const float zf = fminf(fmaxf(bb[t] * 32.f, 0.f), 31.999998f);
        const int x0 = (int)xf, y0 = (int)yf, z0 = (int)zf;
        const float xd = xf - (float)x0, yd = yf - (float)y0, zd = zf - (float)z0;
        const int i00 = (x0 * GN + y0) * GN + z0;
        const uint4 e00 = lut[i00];
        const uint4 e01 = lut[i00 + GN];
        const uint4 e10 = lut[i00 + GG];
        const uint4 e11 = lut[i00 + GG + GN];
        // z blend inside each entry: lo = c(z0), hi = c(z0+1)
        const float a00_0 = bflo(e00.x) + zd * (bflo(e00.z) - bflo(e00.x));
        const float a00_1 = bfhi(e00.x) + zd * (bfhi(e00.z) - bfhi(e00.x));
        const float a00_2 = bflo(e00.y) + zd * (bflo(e00.w) - bflo(e00.y));
        const float a01_0 = bflo(e01.x) + zd * (bflo(e01.z) - bflo(e01.x));
        const float a01_1 = bfhi(e01.x) + zd * (bfhi(e01.z) - bfhi(e01.x));
        const float a01_2 = bflo(e01.y) + zd * (bflo(e01.w) - bflo(e01.y));
        const float a10_0 = bflo(e10.x) + zd * (bflo(e10.z) - bflo(e10.x));
        const float a10_1 = bfhi(e10.x) + zd * (bfhi(e10.z) - bfhi(e10.x));
        const float a10_2 = bflo(e10.y) + zd * (bflo(e10.w) - bflo(e10.y));
        const float a11_0 = bflo(e11.x) + zd * (bflo(e11.z) - bflo(e11.x));
        const float a11_1 = bfhi(e11.x) + zd * (bfhi(e11.z) - bfhi(e11.x));
        const float a11_2 = bflo(e11.y) + zd * (bflo(e11.w) - bflo(e11.y));
        // y blend
        const float b0_0 = a00_0 + yd * (a01_0 - a00_0);
        const float b0_1 = a00_1 + yd * (a01_1 - a00_1);
        const float b0_2 = a00_2 + yd * (a01_2 - a00_2);
        const float b1_0 = a10_0 + yd * (a11_0 - a10_0);
        const float b1_1 = a10_1 + yd * (a11_1 - a10_1);
        const float b1_2 = a10_2 + yd * (a11_2 - a10_2);
        // x blend
        o0[t] = b0_0 + xd * (b1_0 - b0_0);
        o1[t] = b0_1 + xd * (b1_1 - b0_1);
        o2[t] = b0_2 + xd * (b1_2 - b0_2);
    }
    float4* ob = (float4*)(dout + (size_t)b * 3 * NPIX);
    ob[q]             = make_float4(o0[0], o0[1], o0[2], o0[3]);
    ob[NPIX4 + q]     = make_float4(o1[0], o1[1], o1[2], o1[3]);
    ob[2 * NPIX4 + q] = make_float4(o2[0], o2[1], o2[2], o2[3]);
}

extern "C" void kernel_launch(void* const* d_in, const int* in_sizes, int n_in,
                              void* d_out, int out_size, void* d_ws, size_t ws_size,
                              hipStream_t stream)
{
    const float* img_lr   = (const float*)d_in[0];
    const float* img_full = (const float*)d_in[1];
    const float* bases    = (const float*)d_in[2];
    const float* wp_c1_w  = (const float*)d_in[3];
    const float* wp_c1_b  = (const float*)d_in[4];
    const float* wp_c2_w  = (const float*)d_in[5];
    const float* wp_c2_b  = (const float*)d_in[6];
    const float* wp_fc_w  = (const float*)d_in[7];
    const float* wp_fc_b  = (const float*)d_in[8];
    const float* rp_c1_w  = (const float*)d_in[9];
    const float* rp_c1_b  = (const float*)d_in[10];
    const float* rp_c2_w  = (const float*)d_in[11];
    const float* rp_c2_b  = (const float*)d_in[12];
    const float* fcu_w    = (const float*)d_in[13];
    const float* fcu_b    = (const float*)d_in[14];
    const float* fcv_w    = (const float*)d_in[15];
    const float* fcv_b    = (const float*)d_in[16];
    const float* fcw_w    = (const float*)d_in[17];
    const float* fcw_b    = (const float*)d_in[18];
    const float* fcc_w    = (const float*)d_in[19];
    const float* fcc_b    = (const float*)d_in[20];
    float* ws  = (float*)d_ws;
    float* out = (float*)d_out;

    // zero the accumulated stats (means + |delta| sum); ws is poisoned 0xAA
    hipMemsetAsync(ws + WS_STATS, 0, 257 * sizeof(float), stream);

    conv1_kernel<<<dim3(64, 64, 2), 256, 0, stream>>>(
        img_lr, wp_c1_w, wp_c1_b, rp_c1_w, rp_c1_b, ws);
    conv2_kernel<<<dim3(16, 128, 2), 256, 0, stream>>>(
        wp_c2_w, wp_c2_b, rp_c2_w, rp_c2_b, ws);
    head_kernel<<<dim3(13), 256, 0, stream>>>(
        wp_fc_w, wp_fc_b, fcu_w, fcu_b, fcv_w, fcv_b, fcw_w, fcw_b, fcc_w, fcc_b,
        ws, out);
    lut_build_kernel<<<dim3((BATCH * GGG + 255) / 256), 256, 0, stream>>>(bases, ws, out);
    dnorm_kernel<<<1, 1, 0, stream>>>(ws, out);
    apply_kernel<<<dim3(BATCH * NPIX4 / 256), 256, 0, stream>>>(img_full, ws, out);
}